// Round 6
// baseline (269.072 us; speedup 1.0000x reference)
//
#include <hip/hip_runtime.h>
#include <hip/hip_bf16.h>
#include <stdint.h>

typedef __attribute__((ext_vector_type(8))) short s16x8;           // MFMA A/B frag: 8 bf16
typedef __attribute__((ext_vector_type(4))) float f32x4;           // MFMA C/D frag / fp32 vec4
typedef __attribute__((ext_vector_type(8))) unsigned short u16x8;  // 16B vector
typedef __attribute__((ext_vector_type(4))) unsigned short u16x4;  // 8B vector

__device__ __forceinline__ float bf2f(unsigned short u) {
  union { uint32_t u; float f; } v; v.u = ((uint32_t)u) << 16; return v.f;
}
__device__ __forceinline__ unsigned short f2bf(float f) {
  union { float f; uint32_t u; } v; v.f = f;
  uint32_t u = v.u;
  return (unsigned short)((u + 0x7fffu + ((u >> 16) & 1u)) >> 16);  // RNE
}
__device__ __forceinline__ void load_lds16(const void* g, void* l) {
  __builtin_amdgcn_global_load_lds(
      (const __attribute__((address_space(1))) void*)g,
      (__attribute__((address_space(3))) void*)l, 16, 0, 0);
}

template <int N>
__device__ __forceinline__ void vmw() {
  if constexpr (N == 0) asm volatile("s_waitcnt vmcnt(0)" ::: "memory");
  else if constexpr (N == 1) asm volatile("s_waitcnt vmcnt(1)" ::: "memory");
  else if constexpr (N == 2) asm volatile("s_waitcnt vmcnt(2)" ::: "memory");
  else if constexpr (N == 3) asm volatile("s_waitcnt vmcnt(3)" ::: "memory");
  else if constexpr (N == 4) asm volatile("s_waitcnt vmcnt(4)" ::: "memory");
  else if constexpr (N == 5) asm volatile("s_waitcnt vmcnt(5)" ::: "memory");
  else if constexpr (N == 6) asm volatile("s_waitcnt vmcnt(6)" ::: "memory");
  else if constexpr (N == 7) asm volatile("s_waitcnt vmcnt(7)" ::: "memory");
  else asm volatile("s_waitcnt vmcnt(8)" ::: "memory");
}
#define SBAR() asm volatile("s_barrier" ::: "memory")

// PACKED LAYOUT: matrix [R][Kd] -> tiles 64r x 64k. Tile (rt,kt) at ushort
// offset (rt*(Kd/64)+kt)*4096; within tile: plane kb at kb*512, row r at r*8.
// A-tiles are stored SLOT-PERMUTED: tile rt lives at slot sigma(rt), swapping
// the middle third [16,32) with the last third [32,48). This parks A2 (the
// rows K3 needs) at bytes [37.75M,44.04M) of the Abp region, so the split-K
// partial buffers can overlay the dead head of the workspace.
__device__ __forceinline__ int sigma(int rt) {
  return rt < 16 ? rt : (rt < 32 ? rt + 16 : rt - 16);
}

// SCHEDULE NOTE (R4 post-mortem): the phase-interleaved loop with 2 barriers
// per phase measured 88-91 us at BM=192; a 1-barrier-per-tile variant measured
// 118 us (MfmaUtil 37.5 -> 27.9). Do not remove the phase barriers.
// R5 post-mortem: at BM=64 the per-tile fixed cost makes K3 as slow as K1
// (91 us for 1/3 the FLOPs) -> split-K (MODE 1) with fp32 partials.

// ---------------------------------------------------------------------------
// P0: merged prep. blocks [0,3072): transpose x -> Xtp packed.
//     blocks [3072,5376): pack A -> Abp (sigma slots). block 5376: W/b -> Wb.
// ---------------------------------------------------------------------------
__global__ __launch_bounds__(256) void k_prep(const void* __restrict__ xin,
                                              const void* __restrict__ Ain,
                                              const void* __restrict__ W0,
                                              const void* __restrict__ b0,
                                              const void* __restrict__ W1,
                                              const void* __restrict__ b1,
                                              unsigned short* __restrict__ xtp,
                                              unsigned short* __restrict__ Abp,
                                              unsigned short* __restrict__ wb) {
  __shared__ __align__(16) unsigned short sh[64 * 65];  // 4160: fits both tiles
  const int t = threadIdx.x;
  const int bid = blockIdx.x;
  // inline dtype sniff (HW-validated heuristic): fp32 exponents cluster >150
  int fp;
  {
    uint32_t u = ((const uint32_t*)xin)[(t & 63) * 97 + 1];
    int e = (u >> 7) & 0xFF;
    unsigned long long m = __ballot(e > 150);
    fp = (__popcll(m) > 6) ? 1 : 0;
  }

  if (bid < 3072) {
    // ---- transpose: x (3072 w x 4096 m) -> Xtp packed (rows m, k=w) ----
    const int w0 = (bid % 48) * 64;
    const int m0 = (bid / 48) * 64;
    if (fp) {
      const float* xf = (const float*)xin;
#pragma unroll
      for (int rep = 0; rep < 4; ++rep) {
        int vi = t + rep * 256;
        int r = vi >> 4;                // w-local
        int c4 = (vi & 15) * 4;        // m-local
        f32x4 v = *(const f32x4*)(xf + (uint64_t)(w0 + r) * 4096 + m0 + c4);
#pragma unroll
        for (int u = 0; u < 4; ++u) sh[(c4 + u) * 65 + r] = f2bf(v[u]);
      }
    } else {
      const unsigned short* xb = (const unsigned short*)xin;
#pragma unroll
      for (int rep = 0; rep < 2; ++rep) {
        int vi = t + rep * 256;
        int r = vi >> 3;
        int c8 = (vi & 7) * 8;
        u16x8 v = *(const u16x8*)(xb + (uint64_t)(w0 + r) * 4096 + m0 + c8);
#pragma unroll
        for (int u = 0; u < 8; ++u) sh[(c8 + u) * 65 + r] = v[u];
      }
    }
    __syncthreads();
    unsigned short* dst = xtp + ((uint64_t)(m0 >> 6) * 48 + (w0 >> 6)) * 4096;
#pragma unroll
    for (int rep = 0; rep < 2; ++rep) {
      int vi = t + rep * 256;           // [0,512)
      int kb = vi >> 6, r = vi & 63;
      u16x8 v;
#pragma unroll
      for (int u = 0; u < 8; ++u) v[u] = sh[r * 65 + kb * 8 + u];
      *(u16x8*)(dst + kb * 512 + r * 8) = v;
    }
  } else if (bid < 5376) {
    // ---- pack A (3072x3072) -> Abp at slot sigma(rt) ----
    const int b2 = bid - 3072;
    const int kt = b2 % 48, rt = b2 / 48;
    if (fp) {
      const float* Af = (const float*)Ain;
#pragma unroll
      for (int rep = 0; rep < 4; ++rep) {
        int vi = t + rep * 256;
        int r = vi >> 4;
        int c4 = (vi & 15) * 4;
        f32x4 v = *(const f32x4*)(Af + (uint64_t)(rt * 64 + r) * 3072 + kt * 64 + c4);
        int kb = c4 >> 3, e = c4 & 7;
#pragma unroll
        for (int u = 0; u < 4; ++u) sh[kb * 520 + r * 8 + e + u] = f2bf(v[u]);
      }
    } else {
      const unsigned short* Ab16 = (const unsigned short*)Ain;
#pragma unroll
      for (int rep = 0; rep < 2; ++rep) {
        int vi = t + rep * 256;
        int r = vi >> 3;
        int c8 = (vi & 7) * 8;
        u16x8 v = *(const u16x8*)(Ab16 + (uint64_t)(rt * 64 + r) * 3072 + kt * 64 + c8);
#pragma unroll
        for (int u = 0; u < 8; ++u) sh[(c8 >> 3) * 520 + r * 8 + u] = v[u];
      }
    }
    __syncthreads();
    unsigned short* dst = Abp + ((uint64_t)sigma(rt) * 48 + kt) * 4096;
#pragma unroll
    for (int rep = 0; rep < 2; ++rep) {
      int vi = t + rep * 256;
      int kb = vi >> 6, r = vi & 63;
      u16x8 v;
#pragma unroll
      for (int u = 0; u < 8; ++u) v[u] = sh[kb * 520 + r * 8 + u];
      *(u16x8*)(dst + kb * 512 + r * 8) = v;
    }
  } else {
    // ---- W0,b0,W1,b1 -> contiguous bf16 block wb[16640] ----
    for (int i = t; i < 16640; i += 256) {
      const void* src; int off;
      if (i < 8192)        { src = W0; off = i; }
      else if (i < 8320)   { src = b0; off = i - 8192; }
      else if (i < 16512)  { src = W1; off = i - 8320; }
      else                 { src = b1; off = i - 16512; }
      wb[i] = fp ? f2bf(((const float*)src)[off]) : ((const unsigned short*)src)[off];
    }
  }
}

// ---------------------------------------------------------------------------
// Fused NT GEMM — R2-validated phase-interleaved loop, counted vmcnt, 4-deep
// ring, prefetch 3 ahead. MODE 0: full K (96 tiles) + conv/GLU epilogue ->
// packed H. MODE 1 (split-K): blockIdx.x = (vblk<<1)|half, BM=128, 48 tiles
// starting at half*48; writes raw fp32 GEMM partials to P0/P1 (no epilogue).
// ---------------------------------------------------------------------------
template <int BM, int MODE>
__global__ __launch_bounds__(512, 2) void k_gemm_glu6(
    const unsigned short* __restrict__ Am,
    const unsigned short* __restrict__ Bm,
    const unsigned short* __restrict__ W,
    const unsigned short* __restrict__ bias,
    unsigned short* __restrict__ H,
    float* __restrict__ Pout0,
    float* __restrict__ Pout1,
    int Vtot) {
  constexpr int KT64 = 48;                 // packed 64k tiles in K (stride)
  constexpr int IF  = BM / 32;             // A frags per wave (wave M = BM/2)
  constexpr int NPH = (IF > 4) ? 2 : 1;    // phases per K-tile
  constexpr int IPH = IF / NPH;            // A frags per phase
  constexpr int APL = (BM / 64) * 4;       // A planes per 32k K-tile
  constexpr int P   = APL + 16;            // total planes per K-tile (B=16)
  constexpr int QF  = P / 8;               // full staging rounds per wave
  constexpr int QR  = P - QF * 8;          // waves with one extra plane
  constexpr int PPW = QF + (QR ? 1 : 0);
  constexpr int BUFS = P * 512;            // ushorts per ring slot
  constexpr int NRB = BM / 16;             // epilogue 16-row blocks
  constexpr int EPL = BM * 264;            // epilogue G staging (ushorts)
  constexpr int SME = (MODE == 1) ? 4 * BUFS
                                  : ((4 * BUFS > EPL) ? 4 * BUFS : EPL);

  __shared__ __align__(16) unsigned short smem[SME];

  const int t    = threadIdx.x;
  const int lane = t & 63;
  const int wid  = t >> 6;
  const int wV   = wid >> 2;   // 0..1 : v-half of tile
  const int wM   = wid & 3;    // 0..3 : 64-wide m-slice
  const int fr   = lane & 15;
  const int q4   = lane >> 4;
  const int m0   = blockIdx.y * 256;
  const int brt0 = m0 >> 6;

  int v0, kt0, ntk, artB;
  if constexpr (MODE == 1) {
    v0   = (blockIdx.x >> 1) * BM;   // v relative to A2's first row
    kt0  = (blockIdx.x & 1) * 48;    // K half
    ntk  = 48;
    artB = 16;                       // A2 = original rt 16..31
  } else {
    v0 = blockIdx.x * BM; kt0 = 0; ntk = 96; artB = 0;
  }
  const int art0 = artB + (v0 >> 6);

  // ---- staging descriptors: plane pi = wid + 8q, round-robin over waves ----
  const int myq = QF + ((QR && wid < QR) ? 1 : 0);
  const unsigned short* srcb[PPW];
  int ldso[PPW];
#pragma unroll
  for (int q = 0; q < PPW; ++q) {
    int pi = wid + 8 * q;
    if (pi >= P) pi = P - 1;  // inert (guarded by q<myq at issue)
    const int isA = pi < APL;
    const int rtl = (isA ? pi : pi - APL) >> 2;
    const int pb  = pi & 3;
    const unsigned short* base =
        isA ? (Am + (uint64_t)sigma(art0 + rtl) * KT64 * 4096)
            : (Bm + (uint64_t)(brt0 + rtl) * KT64 * 4096);
    srcb[q] = base + pb * 512 + lane * 8;  // per-lane 16B chunk
    ldso[q] = pi * 512;                    // wave-uniform LDS plane
  }

  // ---- fragment LDS offsets (within ring slot) ----
  int aoff[IF], boff[4];
#pragma unroll
  for (int i = 0; i < IF; ++i) {
    const int row = wV * (BM / 2) + i * 16 + fr;
    aoff[i] = ((row >> 6) * 4 + q4) * 512 + (row & 63) * 8;
  }
#pragma unroll
  for (int j = 0; j < 4; ++j)
    boff[j] = (APL + wM * 4 + q4) * 512 + (j * 16 + fr) * 8;

  f32x4 acc[IF][4] = {};

  // ---- prologue: stage K-tiles kt0..kt0+2 into ring slots 0..2 ----
#pragma unroll
  for (int pt = 0; pt < 3; ++pt)
#pragma unroll
    for (int q = 0; q < PPW; ++q)
      if (q < myq)
        load_lds16(srcb[q] + (uint64_t)(kt0 + pt) * 2048, smem + pt * BUFS + ldso[q]);
  if (QR && wid < QR) { vmw<2 * (QF + 1)>(); } else { vmw<2 * QF>(); }  // tile 0 landed
  SBAR();

  // ---- main loop: compute tile tt, prefetch tile tt+3 (R2 structure) ----
#pragma unroll 4
  for (int tt = 0; tt < ntk; ++tt) {
    const unsigned short* buf = smem + (tt & 3) * BUFS;
    s16x8 bfr[4];
#pragma unroll
    for (int ph = 0; ph < NPH; ++ph) {
      if (ph == 0) {
#pragma unroll
        for (int j = 0; j < 4; ++j)
          bfr[j] = *(const s16x8*)(buf + boff[j]);
      }
      s16x8 afr[IPH];
#pragma unroll
      for (int ii = 0; ii < IPH; ++ii)
        afr[ii] = *(const s16x8*)(buf + aoff[ph * IPH + ii]);
      if (tt + 3 < ntk) {
        unsigned short* dst = smem + ((tt + 3) & 3) * BUFS;
#pragma unroll
        for (int q = 0; q < PPW; ++q)
          if ((q % NPH) == ph && q < myq)
            load_lds16(srcb[q] + (uint64_t)(kt0 + tt + 3) * 2048, dst + ldso[q]);
      }
      SBAR();
      __builtin_amdgcn_s_setprio(1);
#pragma unroll
      for (int ii = 0; ii < IPH; ++ii)
#pragma unroll
        for (int j = 0; j < 4; ++j)
          acc[ph * IPH + ii][j] = __builtin_amdgcn_mfma_f32_16x16x32_bf16(
              afr[ii], bfr[j], acc[ph * IPH + ii][j], 0, 0, 0);
      __builtin_amdgcn_s_setprio(0);
      if (ph == NPH - 1) {
        if (tt + 3 < ntk) {        // leave tiles tt+2, tt+3 in flight
          if (QR && wid < QR) { vmw<2 * (QF + 1)>(); } else { vmw<2 * QF>(); }
        } else if (tt + 2 < ntk) { // leave tile tt+2 in flight
          if (QR && wid < QR) { vmw<QF + 1>(); } else { vmw<QF>(); }
        } else {
          vmw<0>();
        }
      }
      SBAR();
    }
  }

  if constexpr (MODE == 1) {
    // ---- split-K partial writeback: raw fp32 G2 partial [1024][4096] ----
    float* Pout = (blockIdx.x & 1) ? Pout1 : Pout0;
#pragma unroll
    for (int i = 0; i < IF; ++i)
#pragma unroll
      for (int j = 0; j < 4; ++j) {
        const int col = wM * 64 + j * 16 + fr;
#pragma unroll
        for (int r = 0; r < 4; ++r) {
          const int row = wV * (BM / 2) + i * 16 + q4 * 4 + r;
          Pout[(uint64_t)(v0 + row) * 4096 + m0 + col] = acc[i][j][r];
        }
      }
    return;
  } else {
    // ---- epilogue: G-tile -> LDS (stride 264), conv + GLU, packed H ----
    __syncthreads();
    {
      const int rr = q4 * 4;
#pragma unroll
      for (int i = 0; i < IF; ++i)
#pragma unroll
        for (int j = 0; j < 4; ++j) {
          const int col = wM * 64 + j * 16 + fr;
#pragma unroll
          for (int r = 0; r < 4; ++r) {
            const int row = wV * (BM / 2) + i * 16 + rr + r;
            smem[row * 264 + col] = f2bf(acc[i][j][r]);
          }
        }
    }
    __syncthreads();

    s16x8 wf[2][8];
#pragma unroll
    for (int ksi = 0; ksi < 2; ++ksi)
#pragma unroll
      for (int j = 0; j < 8; ++j)
        wf[ksi][j] = *(const s16x8*)(W + (j * 16 + fr) * 64 + ksi * 32 + q4 * 8);
    float bj[8];
#pragma unroll
    for (int j = 0; j < 8; ++j) bj[j] = bf2f(bias[j * 16 + fr]);

    const int Vt = Vtot >> 6;
#pragma unroll
    for (int rep = 0; rep < (NRB + 7) / 8; ++rep) {
      const int rb = rep * 8 + wid;
      if (rb < NRB) {
#pragma unroll
        for (int bb = 0; bb < 4; ++bb) {
          f32x4 acc2[8] = {};
#pragma unroll
          for (int ksi = 0; ksi < 2; ++ksi) {
            s16x8 af = *(const s16x8*)(smem + (rb * 16 + fr) * 264 + bb * 64 +
                                       ksi * 32 + q4 * 8);
#pragma unroll
            for (int j = 0; j < 8; ++j)
              acc2[j] = __builtin_amdgcn_mfma_f32_16x16x32_bf16(af, wf[ksi][j],
                                                                acc2[j], 0, 0, 0);
          }
          const int v = v0 + rb * 16 + q4 * 4;
#pragma unroll
          for (int j = 0; j < 4; ++j) {
            u16x4 pk;
#pragma unroll
            for (int r = 0; r < 4; ++r) {
              float lhs = acc2[j][r] + bj[j];
              float rhs = acc2[j + 4][r] + bj[j + 4];
              float sg = 1.0f / (1.0f + __expf(-rhs));
              pk[r] = f2bf(lhs * sg);
            }
            const int o = j * 16 + fr;
            const int hrow = m0 + bb * 64 + o;
            *(u16x4*)(H + ((uint64_t)(hrow >> 6) * Vt + (v >> 6)) * 4096 +
                      ((v >> 3) & 7) * 512 + (hrow & 63) * 8 + (v & 7)) = pk;
          }
        }
      }
    }
  }
}

// ---------------------------------------------------------------------------
// Final pass: G2 = P0+P1 (fp32), conv2 + GLU, max with H1[., 1024+v], fp32
// out. Block = 64 v-rows x 256 m-cols; 8 waves: wave (rb=wid&3) handles
// bb-pair (wid>>2)*2..+1. Epilogue math identical to the validated FUSEMAX.
// ---------------------------------------------------------------------------
__global__ __launch_bounds__(512) void k_glufin(const float* __restrict__ P0f,
                                                const float* __restrict__ P1f,
                                                const unsigned short* __restrict__ W,
                                                const unsigned short* __restrict__ bias,
                                                const unsigned short* __restrict__ Hprev,
                                                float* __restrict__ outp) {
  __shared__ __align__(16) unsigned short g[64 * 264];
  const int t    = threadIdx.x;
  const int lane = t & 63;
  const int wid  = t >> 6;
  const int fr   = lane & 15;
  const int q4   = lane >> 4;
  const int v0   = blockIdx.x * 64;
  const int m0   = blockIdx.y * 256;

  // stage G2 = P0+P1 as bf16 into [64][264]
#pragma unroll
  for (int rep = 0; rep < 8; ++rep) {
    int vi = t + rep * 512;
    int row = vi >> 6;
    int c4 = (vi & 63) * 4;
    uint64_t idx = (uint64_t)(v0 + row) * 4096 + m0 + c4;
    f32x4 a = *(const f32x4*)(P0f + idx);
    f32x4 b = *(const f32x4*)(P1f + idx);
#pragma unroll
    for (int u = 0; u < 4; ++u) g[row * 264 + c4 + u] = f2bf(a[u] + b[u]);
  }
  __syncthreads();

  s16x8 wf[2][8];
#pragma unroll
  for (int ksi = 0; ksi < 2; ++ksi)
#pragma unroll
    for (int j = 0; j < 8; ++j)
      wf[ksi][j] = *(const s16x8*)(W + (j * 16 + fr) * 64 + ksi * 32 + q4 * 8);
  float bj[8];
#pragma unroll
  for (int j = 0; j < 8; ++j) bj[j] = bf2f(bias[j * 16 + fr]);

  const int rb = wid & 3;
#pragma unroll
  for (int bb2 = 0; bb2 < 2; ++bb2) {
    const int bb = (wid >> 2) * 2 + bb2;
    f32x4 acc2[8] = {};
#pragma unroll
    for (int ksi = 0; ksi < 2; ++ksi) {
      s16x8 af = *(const s16x8*)(g + (rb * 16 + fr) * 264 + bb * 64 +
                                 ksi * 32 + q4 * 8);
#pragma unroll
      for (int j = 0; j < 8; ++j)
        acc2[j] = __builtin_amdgcn_mfma_f32_16x16x32_bf16(af, wf[ksi][j],
                                                          acc2[j], 0, 0, 0);
    }
    const int v = v0 + rb * 16 + q4 * 4;
#pragma unroll
    for (int j = 0; j < 4; ++j) {
      const int o = j * 16 + fr;
      const int hrow = m0 + bb * 64 + o;
      const int c = 1024 + v;  // H1 col; Vt of H1 is 48
      u16x4 hv = *(const u16x4*)(Hprev +
          ((uint64_t)(hrow >> 6) * 48 + (c >> 6)) * 4096 +
          ((c >> 3) & 7) * 512 + (hrow & 63) * 8 + (c & 7));
      float* op = outp + (uint64_t)v * 4096 + hrow;
#pragma unroll
      for (int r = 0; r < 4; ++r) {
        float lhs = acc2[j][r] + bj[j];
        float rhs = acc2[j + 4][r] + bj[j + 4];
        float sg = 1.0f / (1.0f + __expf(-rhs));
        op[(uint64_t)r * 4096] = fmaxf(lhs * sg, bf2f(hv[r]));
      }
    }
  }
}

// ---------------------------------------------------------------------------
extern "C" void kernel_launch(void* const* d_in, const int* in_sizes, int n_in,
                              void* d_out, int out_size, void* d_ws, size_t ws_size,
                              hipStream_t stream) {
  (void)in_sizes; (void)n_in; (void)out_size; (void)ws_size;
  const void* x  = d_in[0];  // [3072][64][64]
  const void* A  = d_in[1];  // [3072][3072]
  const void* W0 = d_in[2];  // [128][64]
  const void* b0 = d_in[3];  // [128]
  const void* W1 = d_in[4];  // [128][64]
  const void* b1 = d_in[5];  // [128]
  float* out = (float*)d_out;  // [1024][64][64] fp32

  char* ws = (char*)d_ws;
  unsigned short* Xtp = (unsigned short*)(ws + 0);         // 25165824 B (dead after K1f)
  unsigned short* Abp = (unsigned short*)(ws + 25165824);  // 18874368 B (sigma slots)
  unsigned short* Wb  = (unsigned short*)(ws + 44040192);  // 33280 B
  unsigned short* H1p = (unsigned short*)(ws + 44105728);  // 25165824 B -> end 69271552
  // split-K partials overlay dead space after K1f: Xtp + Abp head.
  // A2 (sigma slots 32..47) lives at abs [37748736, 44040192) -> disjoint.
  float* Pk0 = (float*)(ws + 0);          // 16777216 B
  float* Pk1 = (float*)(ws + 16777216);   // 16777216 B -> end 33554432

  // P0: transpose (3072 blocks) + packA (2304, sigma) + cvtW (1)
  k_prep<<<5377, 256, 0, stream>>>(x, A, W0, b0, W1, b1, Xtp, Abp, Wb);
  // K1f: H1 = GLU(W0.(A.Xt^T)+b0), v covers 3072. 192x256 tiles, 256 blocks.
  k_gemm_glu6<192, 0><<<dim3(16, 16), 512, 0, stream>>>(
      Abp, Xtp, Wb, Wb + 8192, H1p, nullptr, nullptr, 3072);
  // K3s: split-K GEMM partials of A2.H1^T. blockIdx.x=(vblk<<1)|half,
  // BM=128, 48 K-tiles per half -> 256 blocks = full chip.
  k_gemm_glu6<128, 1><<<dim3(16, 16), 512, 0, stream>>>(
      Abp, H1p, nullptr, nullptr, nullptr, Pk0, Pk1, 1024);
  // Final: G2=P0+P1, conv2+GLU, max vs H1 middle third, fp32 out.
  k_glufin<<<dim3(16, 16), 512, 0, stream>>>(Pk0, Pk1, Wb + 8320, Wb + 16512,
                                             H1p, out);
}

// Round 8
// 265.785 us; speedup vs baseline: 1.0124x; 1.0124x over previous
//
#include <hip/hip_runtime.h>
#include <hip/hip_bf16.h>
#include <stdint.h>

typedef __attribute__((ext_vector_type(8))) short s16x8;           // MFMA A/B frag: 8 bf16
typedef __attribute__((ext_vector_type(4))) float f32x4;           // MFMA C/D frag / fp32 vec4
typedef __attribute__((ext_vector_type(8))) unsigned short u16x8;  // 16B vector
typedef __attribute__((ext_vector_type(4))) unsigned short u16x4;  // 8B vector

__device__ __forceinline__ float bf2f(unsigned short u) {
  union { uint32_t u; float f; } v; v.u = ((uint32_t)u) << 16; return v.f;
}
__device__ __forceinline__ unsigned short f2bf(float f) {
  union { float f; uint32_t u; } v; v.f = f;
  uint32_t u = v.u;
  return (unsigned short)((u + 0x7fffu + ((u >> 16) & 1u)) >> 16);  // RNE
}
__device__ __forceinline__ void load_lds16(const void* g, void* l) {
  __builtin_amdgcn_global_load_lds(
      (const __attribute__((address_space(1))) void*)g,
      (__attribute__((address_space(3))) void*)l, 16, 0, 0);
}

template <int N>
__device__ __forceinline__ void vmw() {
  if constexpr (N == 0) asm volatile("s_waitcnt vmcnt(0)" ::: "memory");
  else if constexpr (N == 1) asm volatile("s_waitcnt vmcnt(1)" ::: "memory");
  else if constexpr (N == 2) asm volatile("s_waitcnt vmcnt(2)" ::: "memory");
  else if constexpr (N == 3) asm volatile("s_waitcnt vmcnt(3)" ::: "memory");
  else if constexpr (N == 4) asm volatile("s_waitcnt vmcnt(4)" ::: "memory");
  else if constexpr (N == 5) asm volatile("s_waitcnt vmcnt(5)" ::: "memory");
  else if constexpr (N == 6) asm volatile("s_waitcnt vmcnt(6)" ::: "memory");
  else if constexpr (N == 7) asm volatile("s_waitcnt vmcnt(7)" ::: "memory");
  else asm volatile("s_waitcnt vmcnt(8)" ::: "memory");
}
#define SBAR() asm volatile("s_barrier" ::: "memory")

// PACKED LAYOUT: matrix [R][Kd] -> tiles 64r x 64k. Tile (rt,kt) at ushort
// offset (rt*(Kd/64)+kt)*4096; within tile: plane kb at kb*512, row r at r*8.
//
// SCHEDULE NOTES (R4/R6 post-mortems):
//  * BM=192 (NPH=2): 2-barrier phase loop = 91 us; 1-barrier = 118 us.
//  * BM=64 (NPH=1): 1-barrier loop is ~33 us faster (R4 vs R5 rest-time).
//  * rocprof NAME TRAP: distinct kernel names so dispatches are identifiable.
//  * R7 BUG: A2 offset applied BOTH at launch (Abp+16*48*4096) and in-kernel
//    (art0=16+...) -> K3 read the wrong A third. Offset is applied EXACTLY
//    ONCE: in-kernel art0 = 16 + (v0>>6); launch passes plain Abp.

// ---------------------------------------------------------------------------
// P0: merged prep. blocks [0,3072): transpose x -> Xtp packed.
//     blocks [3072,5376): pack A -> Abp. block 5376: cvt W/b -> Wb.
// dtype sniff folded in (fp32 exponents cluster >150).
// ---------------------------------------------------------------------------
__global__ __launch_bounds__(256) void k_prep(const void* __restrict__ xin,
                                              const void* __restrict__ Ain,
                                              const void* __restrict__ W0,
                                              const void* __restrict__ b0,
                                              const void* __restrict__ W1,
                                              const void* __restrict__ b1,
                                              unsigned short* __restrict__ xtp,
                                              unsigned short* __restrict__ Abp,
                                              unsigned short* __restrict__ wb) {
  __shared__ __align__(16) unsigned short sh[64 * 65];  // 4160: fits both tiles
  const int t = threadIdx.x;
  const int bid = blockIdx.x;
  int fp;
  {
    uint32_t u = ((const uint32_t*)xin)[(t & 63) * 97 + 1];
    int e = (u >> 7) & 0xFF;
    unsigned long long m = __ballot(e > 150);
    fp = (__popcll(m) > 6) ? 1 : 0;
  }

  if (bid < 3072) {
    // ---- transpose: x (3072 w x 4096 m) -> Xtp packed (rows m, k=w) ----
    const int w0 = (bid % 48) * 64;
    const int m0 = (bid / 48) * 64;
    if (fp) {
      const float* xf = (const float*)xin;
#pragma unroll
      for (int rep = 0; rep < 4; ++rep) {
        int vi = t + rep * 256;
        int r = vi >> 4;                // w-local
        int c4 = (vi & 15) * 4;        // m-local
        f32x4 v = *(const f32x4*)(xf + (uint64_t)(w0 + r) * 4096 + m0 + c4);
#pragma unroll
        for (int u = 0; u < 4; ++u) sh[(c4 + u) * 65 + r] = f2bf(v[u]);
      }
    } else {
      const unsigned short* xb = (const unsigned short*)xin;
#pragma unroll
      for (int rep = 0; rep < 2; ++rep) {
        int vi = t + rep * 256;
        int r = vi >> 3;
        int c8 = (vi & 7) * 8;
        u16x8 v = *(const u16x8*)(xb + (uint64_t)(w0 + r) * 4096 + m0 + c8);
#pragma unroll
        for (int u = 0; u < 8; ++u) sh[(c8 + u) * 65 + r] = v[u];
      }
    }
    __syncthreads();
    unsigned short* dst = xtp + ((uint64_t)(m0 >> 6) * 48 + (w0 >> 6)) * 4096;
#pragma unroll
    for (int rep = 0; rep < 2; ++rep) {
      int vi = t + rep * 256;           // [0,512)
      int kb = vi >> 6, r = vi & 63;
      u16x8 v;
#pragma unroll
      for (int u = 0; u < 8; ++u) v[u] = sh[r * 65 + kb * 8 + u];
      *(u16x8*)(dst + kb * 512 + r * 8) = v;
    }
  } else if (bid < 5376) {
    // ---- pack A (3072x3072) -> Abp; LDS bounce planes padded to 520 ----
    const int b2 = bid - 3072;
    const int kt = b2 % 48, rt = b2 / 48;
    if (fp) {
      const float* Af = (const float*)Ain;
#pragma unroll
      for (int rep = 0; rep < 4; ++rep) {
        int vi = t + rep * 256;
        int r = vi >> 4;
        int c4 = (vi & 15) * 4;
        f32x4 v = *(const f32x4*)(Af + (uint64_t)(rt * 64 + r) * 3072 + kt * 64 + c4);
        int kb = c4 >> 3, e = c4 & 7;
#pragma unroll
        for (int u = 0; u < 4; ++u) sh[kb * 520 + r * 8 + e + u] = f2bf(v[u]);
      }
    } else {
      const unsigned short* Ab16 = (const unsigned short*)Ain;
#pragma unroll
      for (int rep = 0; rep < 2; ++rep) {
        int vi = t + rep * 256;
        int r = vi >> 3;
        int c8 = (vi & 7) * 8;
        u16x8 v = *(const u16x8*)(Ab16 + (uint64_t)(rt * 64 + r) * 3072 + kt * 64 + c8);
#pragma unroll
        for (int u = 0; u < 8; ++u) sh[(c8 >> 3) * 520 + r * 8 + u] = v[u];
      }
    }
    __syncthreads();
    unsigned short* dst = Abp + ((uint64_t)rt * 48 + kt) * 4096;
#pragma unroll
    for (int rep = 0; rep < 2; ++rep) {
      int vi = t + rep * 256;
      int kb = vi >> 6, r = vi & 63;
      u16x8 v;
#pragma unroll
      for (int u = 0; u < 8; ++u) v[u] = sh[kb * 520 + r * 8 + u];
      *(u16x8*)(dst + kb * 512 + r * 8) = v;
    }
  } else {
    // ---- W0,b0,W1,b1 -> contiguous bf16 block wb[16640] ----
    for (int i = t; i < 16640; i += 256) {
      const void* src; int off;
      if (i < 8192)        { src = W0; off = i; }
      else if (i < 8320)   { src = b0; off = i - 8192; }
      else if (i < 16512)  { src = W1; off = i - 8320; }
      else                 { src = b1; off = i - 16512; }
      wb[i] = fp ? f2bf(((const float*)src)[off]) : ((const unsigned short*)src)[off];
    }
  }
}

// ---------------------------------------------------------------------------
// K1: fused NT GEMM + conv + GLU -> packed H1. BM=192, 2-phase loop with
// 2 barriers per phase (R5-validated, 91 us), counted vmcnt, 4-deep ring.
// ---------------------------------------------------------------------------
__global__ __launch_bounds__(512, 2) void k1_gemm_glu(
    const unsigned short* __restrict__ Am,
    const unsigned short* __restrict__ Bm,
    const unsigned short* __restrict__ W,
    const unsigned short* __restrict__ bias,
    unsigned short* __restrict__ H) {
  constexpr int BM  = 192;
  constexpr int IF  = 6;
  constexpr int IPH = 3;                   // NPH = 2
  constexpr int APL = 12;
  constexpr int P   = 28;
  constexpr int QF  = 3;                   // QR = 4, PPW = 4
  constexpr int PPW = 4;
  constexpr int BUFS = P * 512;
  constexpr int NT  = 96;
  constexpr int Kt  = 48;
  constexpr int NRB = 12;
  constexpr int SME = 4 * BUFS;            // 57344 > EPL(50688)

  __shared__ __align__(16) unsigned short smem[SME];

  const int t    = threadIdx.x;
  const int lane = t & 63;
  const int wid  = t >> 6;
  const int wV   = wid >> 2;
  const int wM   = wid & 3;
  const int fr   = lane & 15;
  const int q4   = lane >> 4;
  const int v0   = blockIdx.x * BM;
  const int m0   = blockIdx.y * 256;
  const int art0 = v0 >> 6;
  const int brt0 = m0 >> 6;

  const int myq = QF + ((wid < 4) ? 1 : 0);
  const unsigned short* srcb[PPW];
  int ldso[PPW];
#pragma unroll
  for (int q = 0; q < PPW; ++q) {
    int pi = wid + 8 * q;
    if (pi >= P) pi = P - 1;
    const int isA = pi < APL;
    const int rtl = (isA ? pi : pi - APL) >> 2;
    const int pb  = pi & 3;
    const unsigned short* base =
        isA ? (Am + (uint64_t)(art0 + rtl) * Kt * 4096)
            : (Bm + (uint64_t)(brt0 + rtl) * Kt * 4096);
    srcb[q] = base + pb * 512 + lane * 8;
    ldso[q] = pi * 512;
  }

  int aoff[IF], boff[4];
#pragma unroll
  for (int i = 0; i < IF; ++i) {
    const int row = wV * 96 + i * 16 + fr;
    aoff[i] = ((row >> 6) * 4 + q4) * 512 + (row & 63) * 8;
  }
#pragma unroll
  for (int j = 0; j < 4; ++j)
    boff[j] = (APL + wM * 4 + q4) * 512 + (j * 16 + fr) * 8;

  f32x4 acc[IF][4] = {};

#pragma unroll
  for (int pt = 0; pt < 3; ++pt)
#pragma unroll
    for (int q = 0; q < PPW; ++q)
      if (q < myq)
        load_lds16(srcb[q] + pt * 2048, smem + pt * BUFS + ldso[q]);
  if (wid < 4) { vmw<8>(); } else { vmw<6>(); }
  SBAR();

#pragma unroll 4
  for (int tt = 0; tt < NT; ++tt) {
    const unsigned short* buf = smem + (tt & 3) * BUFS;
    s16x8 bfr[4];
#pragma unroll
    for (int ph = 0; ph < 2; ++ph) {
      if (ph == 0) {
#pragma unroll
        for (int j = 0; j < 4; ++j)
          bfr[j] = *(const s16x8*)(buf + boff[j]);
      }
      s16x8 afr[IPH];
#pragma unroll
      for (int ii = 0; ii < IPH; ++ii)
        afr[ii] = *(const s16x8*)(buf + aoff[ph * IPH + ii]);
      if (tt + 3 < NT) {
        unsigned short* dst = smem + ((tt + 3) & 3) * BUFS;
#pragma unroll
        for (int q = 0; q < PPW; ++q)
          if ((q % 2) == ph && q < myq)
            load_lds16(srcb[q] + (uint64_t)(tt + 3) * 2048, dst + ldso[q]);
      }
      SBAR();
      __builtin_amdgcn_s_setprio(1);
#pragma unroll
      for (int ii = 0; ii < IPH; ++ii)
#pragma unroll
        for (int j = 0; j < 4; ++j)
          acc[ph * IPH + ii][j] = __builtin_amdgcn_mfma_f32_16x16x32_bf16(
              afr[ii], bfr[j], acc[ph * IPH + ii][j], 0, 0, 0);
      __builtin_amdgcn_s_setprio(0);
      if (ph == 1) {
        if (tt + 3 < NT) {
          if (wid < 4) { vmw<8>(); } else { vmw<6>(); }
        } else if (tt + 2 < NT) {
          if (wid < 4) { vmw<4>(); } else { vmw<3>(); }
        } else {
          vmw<0>();
        }
      }
      SBAR();
    }
  }

  // ---- epilogue: G-tile -> LDS (stride 264), conv + GLU, packed H ----
  __syncthreads();
  {
    const int rr = q4 * 4;
#pragma unroll
    for (int i = 0; i < IF; ++i)
#pragma unroll
      for (int j = 0; j < 4; ++j) {
        const int col = wM * 64 + j * 16 + fr;
#pragma unroll
        for (int r = 0; r < 4; ++r) {
          const int row = wV * 96 + i * 16 + rr + r;
          smem[row * 264 + col] = f2bf(acc[i][j][r]);
        }
      }
  }
  __syncthreads();

  s16x8 wf[2][8];
#pragma unroll
  for (int ksi = 0; ksi < 2; ++ksi)
#pragma unroll
    for (int j = 0; j < 8; ++j)
      wf[ksi][j] = *(const s16x8*)(W + (j * 16 + fr) * 64 + ksi * 32 + q4 * 8);
  float bj[8];
#pragma unroll
  for (int j = 0; j < 8; ++j) bj[j] = bf2f(bias[j * 16 + fr]);

#pragma unroll
  for (int rep = 0; rep < 2; ++rep) {
    const int rb = rep * 8 + wid;
    if (rb < NRB) {
#pragma unroll
      for (int bb = 0; bb < 4; ++bb) {
        f32x4 acc2[8] = {};
#pragma unroll
        for (int ksi = 0; ksi < 2; ++ksi) {
          s16x8 af = *(const s16x8*)(smem + (rb * 16 + fr) * 264 + bb * 64 +
                                     ksi * 32 + q4 * 8);
#pragma unroll
          for (int j = 0; j < 8; ++j)
            acc2[j] = __builtin_amdgcn_mfma_f32_16x16x32_bf16(af, wf[ksi][j],
                                                              acc2[j], 0, 0, 0);
        }
        const int v = v0 + rb * 16 + q4 * 4;
#pragma unroll
        for (int j = 0; j < 4; ++j) {
          u16x4 pk;
#pragma unroll
          for (int r = 0; r < 4; ++r) {
            float lhs = acc2[j][r] + bj[j];
            float rhs = acc2[j + 4][r] + bj[j + 4];
            float sg = 1.0f / (1.0f + __expf(-rhs));
            pk[r] = f2bf(lhs * sg);
          }
          const int o = j * 16 + fr;
          const int hrow = m0 + bb * 64 + o;
          *(u16x4*)(H + ((uint64_t)(hrow >> 6) * 48 + (v >> 6)) * 4096 +
                    ((v >> 3) & 7) * 512 + (hrow & 63) * 8 + (v & 7)) = pk;
        }
      }
    }
  }
}

// ---------------------------------------------------------------------------
// K3: fused NT GEMM + conv + GLU + max-with-H1 -> fp32 out. BM=64, ONE
// barrier per K-tile (R4-validated for NPH=1), counted vmcnt, 4-deep ring.
// LDS = 80 KB -> 2 blocks/CU. A2 offset applied ONCE here (art0 = 16+...);
// caller passes plain Abp.
// ---------------------------------------------------------------------------
__global__ __launch_bounds__(512, 2) void k3_gemm_glu(
    const unsigned short* __restrict__ Am,
    const unsigned short* __restrict__ Bm,
    const unsigned short* __restrict__ W,
    const unsigned short* __restrict__ bias,
    const unsigned short* __restrict__ Hprev,
    float* __restrict__ outp) {
  constexpr int BM  = 64;
  constexpr int IF  = 2;
  constexpr int APL = 4;
  constexpr int P   = 20;
  constexpr int QF  = 2;                   // QR = 4, PPW = 3
  constexpr int PPW = 3;
  constexpr int BUFS = P * 512;
  constexpr int NT  = 96;
  constexpr int Kt  = 48;
  constexpr int SME = 4 * BUFS;            // 40960 ushorts = 80 KB

  __shared__ __align__(16) unsigned short smem[SME];

  const int t    = threadIdx.x;
  const int lane = t & 63;
  const int wid  = t >> 6;
  const int wV   = wid >> 2;
  const int wM   = wid & 3;
  const int fr   = lane & 15;
  const int q4   = lane >> 4;
  const int v0   = blockIdx.x * BM;
  const int m0   = blockIdx.y * 256;
  const int art0 = 16 + (v0 >> 6);  // A2 = original rt 16..31 (SOLE offset)
  const int brt0 = m0 >> 6;

  const int myq = QF + ((wid < 4) ? 1 : 0);
  const unsigned short* srcb[PPW];
  int ldso[PPW];
#pragma unroll
  for (int q = 0; q < PPW; ++q) {
    int pi = wid + 8 * q;
    if (pi >= P) pi = P - 1;
    const int isA = pi < APL;
    const int rtl = (isA ? pi : pi - APL) >> 2;
    const int pb  = pi & 3;
    const unsigned short* base =
        isA ? (Am + (uint64_t)(art0 + rtl) * Kt * 4096)
            : (Bm + (uint64_t)(brt0 + rtl) * Kt * 4096);
    srcb[q] = base + pb * 512 + lane * 8;
    ldso[q] = pi * 512;
  }

  int aoff[IF], boff[4];
#pragma unroll
  for (int i = 0; i < IF; ++i) {
    const int row = wV * 32 + i * 16 + fr;
    aoff[i] = ((row >> 6) * 4 + q4) * 512 + (row & 63) * 8;
  }
#pragma unroll
  for (int j = 0; j < 4; ++j)
    boff[j] = (APL + wM * 4 + q4) * 512 + (j * 16 + fr) * 8;

  f32x4 acc[IF][4] = {};

#pragma unroll
  for (int pt = 0; pt < 3; ++pt)
#pragma unroll
    for (int q = 0; q < PPW; ++q)
      if (q < myq)
        load_lds16(srcb[q] + pt * 2048, smem + pt * BUFS + ldso[q]);
  if (wid < 4) { vmw<6>(); } else { vmw<4>(); }
  SBAR();

  // ---- main loop: ONE barrier per K-tile (R4 structure) ----
#pragma unroll 4
  for (int tt = 0; tt < NT; ++tt) {
    const unsigned short* buf = smem + (tt & 3) * BUFS;
    s16x8 bfr[4], afr[IF];
#pragma unroll
    for (int j = 0; j < 4; ++j) bfr[j] = *(const s16x8*)(buf + boff[j]);
#pragma unroll
    for (int i = 0; i < IF; ++i) afr[i] = *(const s16x8*)(buf + aoff[i]);
    if (tt + 3 < NT) {
      unsigned short* pdst = smem + ((tt + 3) & 3) * BUFS;
#pragma unroll
      for (int q = 0; q < PPW; ++q)
        if (q < myq)
          load_lds16(srcb[q] + (uint64_t)(tt + 3) * 2048, pdst + ldso[q]);
    }
    __builtin_amdgcn_s_setprio(1);
#pragma unroll
    for (int i = 0; i < IF; ++i)
#pragma unroll
      for (int j = 0; j < 4; ++j)
        acc[i][j] = __builtin_amdgcn_mfma_f32_16x16x32_bf16(afr[i], bfr[j],
                                                            acc[i][j], 0, 0, 0);
    __builtin_amdgcn_s_setprio(0);
    if (tt + 3 < NT) {
      if (wid < 4) { vmw<6>(); } else { vmw<4>(); }
    } else if (tt + 2 < NT) {
      if (wid < 4) { vmw<3>(); } else { vmw<2>(); }
    } else {
      vmw<0>();
    }
    SBAR();
  }

  // ---- epilogue: G-tile -> LDS (stride 264), conv + GLU + max -> fp32 ----
  __syncthreads();
  {
    const int rr = q4 * 4;
#pragma unroll
    for (int i = 0; i < IF; ++i)
#pragma unroll
      for (int j = 0; j < 4; ++j) {
        const int col = wM * 64 + j * 16 + fr;
#pragma unroll
        for (int r = 0; r < 4; ++r) {
          const int row = wV * 32 + i * 16 + rr + r;
          smem[row * 264 + col] = f2bf(acc[i][j][r]);
        }
      }
  }
  __syncthreads();

  s16x8 wf[2][8];
#pragma unroll
  for (int ksi = 0; ksi < 2; ++ksi)
#pragma unroll
    for (int j = 0; j < 8; ++j)
      wf[ksi][j] = *(const s16x8*)(W + (j * 16 + fr) * 64 + ksi * 32 + q4 * 8);
  float bj[8];
#pragma unroll
  for (int j = 0; j < 8; ++j) bj[j] = bf2f(bias[j * 16 + fr]);

  {
    const int rb = wid & 3;          // 4 row-blocks of 16
    const int bbh = wid >> 2;        // bb pair selector
#pragma unroll
    for (int bb2 = 0; bb2 < 2; ++bb2) {
      const int bb = bbh * 2 + bb2;
      f32x4 acc2[8] = {};
#pragma unroll
      for (int ksi = 0; ksi < 2; ++ksi) {
        s16x8 af = *(const s16x8*)(smem + (rb * 16 + fr) * 264 + bb * 64 +
                                   ksi * 32 + q4 * 8);
#pragma unroll
        for (int j = 0; j < 8; ++j)
          acc2[j] = __builtin_amdgcn_mfma_f32_16x16x32_bf16(af, wf[ksi][j],
                                                            acc2[j], 0, 0, 0);
      }
      const int v = v0 + rb * 16 + q4 * 4;
#pragma unroll
      for (int j = 0; j < 4; ++j) {
        const int o = j * 16 + fr;
        const int hrow = m0 + bb * 64 + o;
        const int c = 1024 + v;  // H1 col; Vt of H1 is 48
        u16x4 hv = *(const u16x4*)(Hprev +
            ((uint64_t)(hrow >> 6) * 48 + (c >> 6)) * 4096 +
            ((c >> 3) & 7) * 512 + (hrow & 63) * 8 + (c & 7));
        float* op = outp + (uint64_t)v * 4096 + hrow;
#pragma unroll
        for (int r = 0; r < 4; ++r) {
          float lhs = acc2[j][r] + bj[j];
          float rhs = acc2[j + 4][r] + bj[j + 4];
          float sg = 1.0f / (1.0f + __expf(-rhs));
          op[(uint64_t)r * 4096] = fmaxf(lhs * sg, bf2f(hv[r]));
        }
      }
    }
  }
}

// ---------------------------------------------------------------------------
extern "C" void kernel_launch(void* const* d_in, const int* in_sizes, int n_in,
                              void* d_out, int out_size, void* d_ws, size_t ws_size,
                              hipStream_t stream) {
  (void)in_sizes; (void)n_in; (void)out_size; (void)ws_size;
  const void* x  = d_in[0];  // [3072][64][64]
  const void* A  = d_in[1];  // [3072][3072]
  const void* W0 = d_in[2];  // [128][64]
  const void* b0 = d_in[3];  // [128]
  const void* W1 = d_in[4];  // [128][64]
  const void* b1 = d_in[5];  // [128]
  float* out = (float*)d_out;  // [1024][64][64] fp32

  char* ws = (char*)d_ws;
  unsigned short* Xtp = (unsigned short*)(ws + 0);         // 25165824 B
  unsigned short* Abp = (unsigned short*)(ws + 25165824);  // 18874368 B
  unsigned short* Wb  = (unsigned short*)(ws + 44040192);  // 33280 B
  unsigned short* H1p = (unsigned short*)(ws + 44105728);  // 25165824 B -> end 69271552

  // P0: transpose (3072 blocks) + packA (2304) + cvtW (1)
  k_prep<<<5377, 256, 0, stream>>>(x, A, W0, b0, W1, b1, Xtp, Abp, Wb);
  // K1: H1 = GLU(W0.(A.Xt^T)+b0), 192x256 tiles -> 256 blocks = 1/CU.
  k1_gemm_glu<<<dim3(16, 16), 512, 0, stream>>>(Abp, Xtp, Wb, Wb + 8192, H1p);
  // K3: out = max(H1 mid, GLU(W1.(A2.H1^T)+b1)), 64x256 tiles, 256 blocks.
  // NOTE: plain Abp — the +16-tile A2 offset lives inside k3_gemm_glu.
  k3_gemm_glu<<<dim3(16, 16), 512, 0, stream>>>(
      Abp, H1p, Wb + 8320, Wb + 16512, H1p, out);
}

// Round 9
// 264.996 us; speedup vs baseline: 1.0154x; 1.0030x over previous
//
#include <hip/hip_runtime.h>
#include <hip/hip_bf16.h>
#include <stdint.h>

typedef __attribute__((ext_vector_type(8))) short s16x8;           // MFMA A/B frag: 8 bf16
typedef __attribute__((ext_vector_type(4))) float f32x4;           // MFMA C/D frag / fp32 vec4
typedef __attribute__((ext_vector_type(8))) unsigned short u16x8;  // 16B vector
typedef __attribute__((ext_vector_type(4))) unsigned short u16x4;  // 8B vector

__device__ __forceinline__ float bf2f(unsigned short u) {
  union { uint32_t u; float f; } v; v.u = ((uint32_t)u) << 16; return v.f;
}
__device__ __forceinline__ unsigned short f2bf(float f) {
  union { float f; uint32_t u; } v; v.f = f;
  uint32_t u = v.u;
  return (unsigned short)((u + 0x7fffu + ((u >> 16) & 1u)) >> 16);  // RNE
}
__device__ __forceinline__ void load_lds16(const void* g, void* l) {
  __builtin_amdgcn_global_load_lds(
      (const __attribute__((address_space(1))) void*)g,
      (__attribute__((address_space(3))) void*)l, 16, 0, 0);
}

template <int N>
__device__ __forceinline__ void vmw() {
  if constexpr (N == 0) asm volatile("s_waitcnt vmcnt(0)" ::: "memory");
  else if constexpr (N == 1) asm volatile("s_waitcnt vmcnt(1)" ::: "memory");
  else if constexpr (N == 2) asm volatile("s_waitcnt vmcnt(2)" ::: "memory");
  else if constexpr (N == 3) asm volatile("s_waitcnt vmcnt(3)" ::: "memory");
  else if constexpr (N == 4) asm volatile("s_waitcnt vmcnt(4)" ::: "memory");
  else if constexpr (N == 5) asm volatile("s_waitcnt vmcnt(5)" ::: "memory");
  else if constexpr (N == 6) asm volatile("s_waitcnt vmcnt(6)" ::: "memory");
  else if constexpr (N == 7) asm volatile("s_waitcnt vmcnt(7)" ::: "memory");
  else asm volatile("s_waitcnt vmcnt(8)" ::: "memory");
}
#define SBAR() asm volatile("s_barrier" ::: "memory")

// PACKED LAYOUT: matrix [R][Kd] -> tiles 64r x 64k. Tile (rt,kt) at ushort
// offset (rt*(Kd/64)+kt)*4096; within tile: plane kb at kb*512, row r at r*8.
//
// SCHEDULE NOTES:
//  * K1 BM=192 (NPH=2): 2-barrier phase loop = 91 us; 1-barrier = 118 us.
//  * K3: loop style (1 vs 2 barriers) is ~noise; binding constraint is
//    STAGED BYTES: g_m*|A2| + g_v*|H1| at g_v*g_m=256. R8's 64x256 grid
//    (16,16) staged 504 MB; this 128x128 grid (8,32) stages 403 MB (min).
//  * R7 BUG (fixed): A2 offset applied exactly once, in-kernel art0=16+...
// ---------------------------------------------------------------------------
// P0: merged prep. blocks [0,3072): transpose x -> Xtp packed.
//     blocks [3072,5376): pack A -> Abp. block 5376: cvt W/b -> Wb.
// dtype sniff folded in (fp32 exponents cluster >150).
// ---------------------------------------------------------------------------
__global__ __launch_bounds__(256) void k_prep(const void* __restrict__ xin,
                                              const void* __restrict__ Ain,
                                              const void* __restrict__ W0,
                                              const void* __restrict__ b0,
                                              const void* __restrict__ W1,
                                              const void* __restrict__ b1,
                                              unsigned short* __restrict__ xtp,
                                              unsigned short* __restrict__ Abp,
                                              unsigned short* __restrict__ wb) {
  __shared__ __align__(16) unsigned short sh[64 * 65];  // 4160: fits both tiles
  const int t = threadIdx.x;
  const int bid = blockIdx.x;
  int fp;
  {
    uint32_t u = ((const uint32_t*)xin)[(t & 63) * 97 + 1];
    int e = (u >> 7) & 0xFF;
    unsigned long long m = __ballot(e > 150);
    fp = (__popcll(m) > 6) ? 1 : 0;
  }

  if (bid < 3072) {
    // ---- transpose: x (3072 w x 4096 m) -> Xtp packed (rows m, k=w) ----
    const int w0 = (bid % 48) * 64;
    const int m0 = (bid / 48) * 64;
    if (fp) {
      const float* xf = (const float*)xin;
#pragma unroll
      for (int rep = 0; rep < 4; ++rep) {
        int vi = t + rep * 256;
        int r = vi >> 4;                // w-local
        int c4 = (vi & 15) * 4;        // m-local
        f32x4 v = *(const f32x4*)(xf + (uint64_t)(w0 + r) * 4096 + m0 + c4);
#pragma unroll
        for (int u = 0; u < 4; ++u) sh[(c4 + u) * 65 + r] = f2bf(v[u]);
      }
    } else {
      const unsigned short* xb = (const unsigned short*)xin;
#pragma unroll
      for (int rep = 0; rep < 2; ++rep) {
        int vi = t + rep * 256;
        int r = vi >> 3;
        int c8 = (vi & 7) * 8;
        u16x8 v = *(const u16x8*)(xb + (uint64_t)(w0 + r) * 4096 + m0 + c8);
#pragma unroll
        for (int u = 0; u < 8; ++u) sh[(c8 + u) * 65 + r] = v[u];
      }
    }
    __syncthreads();
    unsigned short* dst = xtp + ((uint64_t)(m0 >> 6) * 48 + (w0 >> 6)) * 4096;
#pragma unroll
    for (int rep = 0; rep < 2; ++rep) {
      int vi = t + rep * 256;           // [0,512)
      int kb = vi >> 6, r = vi & 63;
      u16x8 v;
#pragma unroll
      for (int u = 0; u < 8; ++u) v[u] = sh[r * 65 + kb * 8 + u];
      *(u16x8*)(dst + kb * 512 + r * 8) = v;
    }
  } else if (bid < 5376) {
    // ---- pack A (3072x3072) -> Abp; LDS bounce planes padded to 520 ----
    const int b2 = bid - 3072;
    const int kt = b2 % 48, rt = b2 / 48;
    if (fp) {
      const float* Af = (const float*)Ain;
#pragma unroll
      for (int rep = 0; rep < 4; ++rep) {
        int vi = t + rep * 256;
        int r = vi >> 4;
        int c4 = (vi & 15) * 4;
        f32x4 v = *(const f32x4*)(Af + (uint64_t)(rt * 64 + r) * 3072 + kt * 64 + c4);
        int kb = c4 >> 3, e = c4 & 7;
#pragma unroll
        for (int u = 0; u < 4; ++u) sh[kb * 520 + r * 8 + e + u] = f2bf(v[u]);
      }
    } else {
      const unsigned short* Ab16 = (const unsigned short*)Ain;
#pragma unroll
      for (int rep = 0; rep < 2; ++rep) {
        int vi = t + rep * 256;
        int r = vi >> 3;
        int c8 = (vi & 7) * 8;
        u16x8 v = *(const u16x8*)(Ab16 + (uint64_t)(rt * 64 + r) * 3072 + kt * 64 + c8);
#pragma unroll
        for (int u = 0; u < 8; ++u) sh[(c8 >> 3) * 520 + r * 8 + u] = v[u];
      }
    }
    __syncthreads();
    unsigned short* dst = Abp + ((uint64_t)rt * 48 + kt) * 4096;
#pragma unroll
    for (int rep = 0; rep < 2; ++rep) {
      int vi = t + rep * 256;
      int kb = vi >> 6, r = vi & 63;
      u16x8 v;
#pragma unroll
      for (int u = 0; u < 8; ++u) v[u] = sh[kb * 520 + r * 8 + u];
      *(u16x8*)(dst + kb * 512 + r * 8) = v;
    }
  } else {
    // ---- W0,b0,W1,b1 -> contiguous bf16 block wb[16640] ----
    for (int i = t; i < 16640; i += 256) {
      const void* src; int off;
      if (i < 8192)        { src = W0; off = i; }
      else if (i < 8320)   { src = b0; off = i - 8192; }
      else if (i < 16512)  { src = W1; off = i - 8320; }
      else                 { src = b1; off = i - 16512; }
      wb[i] = fp ? f2bf(((const float*)src)[off]) : ((const unsigned short*)src)[off];
    }
  }
}

// ---------------------------------------------------------------------------
// K1: fused NT GEMM + conv + GLU -> packed H1. BM=192, 2-phase loop with
// 2 barriers per phase (R5-validated, 91 us), counted vmcnt, 4-deep ring.
// ---------------------------------------------------------------------------
__global__ __launch_bounds__(512, 2) void k1_gemm_glu(
    const unsigned short* __restrict__ Am,
    const unsigned short* __restrict__ Bm,
    const unsigned short* __restrict__ W,
    const unsigned short* __restrict__ bias,
    unsigned short* __restrict__ H) {
  constexpr int BM  = 192;
  constexpr int IF  = 6;
  constexpr int IPH = 3;                   // NPH = 2
  constexpr int APL = 12;
  constexpr int P   = 28;
  constexpr int QF  = 3;                   // QR = 4, PPW = 4
  constexpr int PPW = 4;
  constexpr int BUFS = P * 512;
  constexpr int NT  = 96;
  constexpr int Kt  = 48;
  constexpr int NRB = 12;
  constexpr int SME = 4 * BUFS;            // 57344 > EPL(50688)

  __shared__ __align__(16) unsigned short smem[SME];

  const int t    = threadIdx.x;
  const int lane = t & 63;
  const int wid  = t >> 6;
  const int wV   = wid >> 2;
  const int wM   = wid & 3;
  const int fr   = lane & 15;
  const int q4   = lane >> 4;
  const int v0   = blockIdx.x * BM;
  const int m0   = blockIdx.y * 256;
  const int art0 = v0 >> 6;
  const int brt0 = m0 >> 6;

  const int myq = QF + ((wid < 4) ? 1 : 0);
  const unsigned short* srcb[PPW];
  int ldso[PPW];
#pragma unroll
  for (int q = 0; q < PPW; ++q) {
    int pi = wid + 8 * q;
    if (pi >= P) pi = P - 1;
    const int isA = pi < APL;
    const int rtl = (isA ? pi : pi - APL) >> 2;
    const int pb  = pi & 3;
    const unsigned short* base =
        isA ? (Am + (uint64_t)(art0 + rtl) * Kt * 4096)
            : (Bm + (uint64_t)(brt0 + rtl) * Kt * 4096);
    srcb[q] = base + pb * 512 + lane * 8;
    ldso[q] = pi * 512;
  }

  int aoff[IF], boff[4];
#pragma unroll
  for (int i = 0; i < IF; ++i) {
    const int row = wV * 96 + i * 16 + fr;
    aoff[i] = ((row >> 6) * 4 + q4) * 512 + (row & 63) * 8;
  }
#pragma unroll
  for (int j = 0; j < 4; ++j)
    boff[j] = (APL + wM * 4 + q4) * 512 + (j * 16 + fr) * 8;

  f32x4 acc[IF][4] = {};

#pragma unroll
  for (int pt = 0; pt < 3; ++pt)
#pragma unroll
    for (int q = 0; q < PPW; ++q)
      if (q < myq)
        load_lds16(srcb[q] + pt * 2048, smem + pt * BUFS + ldso[q]);
  if (wid < 4) { vmw<8>(); } else { vmw<6>(); }
  SBAR();

#pragma unroll 4
  for (int tt = 0; tt < NT; ++tt) {
    const unsigned short* buf = smem + (tt & 3) * BUFS;
    s16x8 bfr[4];
#pragma unroll
    for (int ph = 0; ph < 2; ++ph) {
      if (ph == 0) {
#pragma unroll
        for (int j = 0; j < 4; ++j)
          bfr[j] = *(const s16x8*)(buf + boff[j]);
      }
      s16x8 afr[IPH];
#pragma unroll
      for (int ii = 0; ii < IPH; ++ii)
        afr[ii] = *(const s16x8*)(buf + aoff[ph * IPH + ii]);
      if (tt + 3 < NT) {
        unsigned short* dst = smem + ((tt + 3) & 3) * BUFS;
#pragma unroll
        for (int q = 0; q < PPW; ++q)
          if ((q % 2) == ph && q < myq)
            load_lds16(srcb[q] + (uint64_t)(tt + 3) * 2048, dst + ldso[q]);
      }
      SBAR();
      __builtin_amdgcn_s_setprio(1);
#pragma unroll
      for (int ii = 0; ii < IPH; ++ii)
#pragma unroll
        for (int j = 0; j < 4; ++j)
          acc[ph * IPH + ii][j] = __builtin_amdgcn_mfma_f32_16x16x32_bf16(
              afr[ii], bfr[j], acc[ph * IPH + ii][j], 0, 0, 0);
      __builtin_amdgcn_s_setprio(0);
      if (ph == 1) {
        if (tt + 3 < NT) {
          if (wid < 4) { vmw<8>(); } else { vmw<6>(); }
        } else if (tt + 2 < NT) {
          if (wid < 4) { vmw<4>(); } else { vmw<3>(); }
        } else {
          vmw<0>();
        }
      }
      SBAR();
    }
  }

  // ---- epilogue: G-tile -> LDS (stride 264), conv + GLU, packed H ----
  __syncthreads();
  {
    const int rr = q4 * 4;
#pragma unroll
    for (int i = 0; i < IF; ++i)
#pragma unroll
      for (int j = 0; j < 4; ++j) {
        const int col = wM * 64 + j * 16 + fr;
#pragma unroll
        for (int r = 0; r < 4; ++r) {
          const int row = wV * 96 + i * 16 + rr + r;
          smem[row * 264 + col] = f2bf(acc[i][j][r]);
        }
      }
  }
  __syncthreads();

  s16x8 wf[2][8];
#pragma unroll
  for (int ksi = 0; ksi < 2; ++ksi)
#pragma unroll
    for (int j = 0; j < 8; ++j)
      wf[ksi][j] = *(const s16x8*)(W + (j * 16 + fr) * 64 + ksi * 32 + q4 * 8);
  float bj[8];
#pragma unroll
  for (int j = 0; j < 8; ++j) bj[j] = bf2f(bias[j * 16 + fr]);

#pragma unroll
  for (int rep = 0; rep < 2; ++rep) {
    const int rb = rep * 8 + wid;
    if (rb < NRB) {
#pragma unroll
      for (int bb = 0; bb < 4; ++bb) {
        f32x4 acc2[8] = {};
#pragma unroll
        for (int ksi = 0; ksi < 2; ++ksi) {
          s16x8 af = *(const s16x8*)(smem + (rb * 16 + fr) * 264 + bb * 64 +
                                     ksi * 32 + q4 * 8);
#pragma unroll
          for (int j = 0; j < 8; ++j)
            acc2[j] = __builtin_amdgcn_mfma_f32_16x16x32_bf16(af, wf[ksi][j],
                                                              acc2[j], 0, 0, 0);
        }
        const int v = v0 + rb * 16 + q4 * 4;
#pragma unroll
        for (int j = 0; j < 4; ++j) {
          u16x4 pk;
#pragma unroll
          for (int r = 0; r < 4; ++r) {
            float lhs = acc2[j][r] + bj[j];
            float rhs = acc2[j + 4][r] + bj[j + 4];
            float sg = 1.0f / (1.0f + __expf(-rhs));
            pk[r] = f2bf(lhs * sg);
          }
          const int o = j * 16 + fr;
          const int hrow = m0 + bb * 64 + o;
          *(u16x4*)(H + ((uint64_t)(hrow >> 6) * 48 + (v >> 6)) * 4096 +
                    ((v >> 3) & 7) * 512 + (hrow & 63) * 8 + (v & 7)) = pk;
        }
      }
    }
  }
}

// ---------------------------------------------------------------------------
// K3: fused NT GEMM + conv + GLU + max-with-H1 -> fp32 out. 128x128 tiles
// (grid 8x32 = 256 blocks, min-staging shape), ONE barrier per K-tile,
// counted vmcnt, 4-deep ring of 16-plane slots (64 KB -> 2 blocks/CU).
// QF=2, QR=0 -> uniform vmcnt across waves. A2 offset applied ONCE here.
// ---------------------------------------------------------------------------
__global__ __launch_bounds__(512, 2) void k3_gemm_glu(
    const unsigned short* __restrict__ Am,
    const unsigned short* __restrict__ Bm,
    const unsigned short* __restrict__ W,
    const unsigned short* __restrict__ bias,
    const unsigned short* __restrict__ Hprev,
    float* __restrict__ outp) {
  constexpr int IF  = 2;                   // A frags/wave (wave M = 32)
  constexpr int APL = 8;                   // A planes per 32k K-tile
  constexpr int P   = 16;                  // + 8 B planes
  constexpr int PPW = 2;                   // QF=2, QR=0
  constexpr int BUFS = P * 512;            // 8192 ushorts per slot
  constexpr int NT  = 96;
  constexpr int Kt  = 48;
  constexpr int SME = 4 * BUFS;            // 32768 ushorts = 64 KB > EPL(17408)

  __shared__ __align__(16) unsigned short smem[SME];

  const int t    = threadIdx.x;
  const int lane = t & 63;
  const int wid  = t >> 6;
  const int wV   = wid >> 1;   // 0..3 : 32-row v-quarter
  const int wM   = wid & 1;    // 0..1 : 64-wide m-slice
  const int fr   = lane & 15;
  const int q4   = lane >> 4;
  const int v0   = blockIdx.x * 128;
  const int m0   = blockIdx.y * 128;
  const int art0 = 16 + (v0 >> 6);  // A2 = original rt 16..31 (SOLE offset)
  const int brt0 = m0 >> 6;

  const unsigned short* srcb[PPW];
  int ldso[PPW];
#pragma unroll
  for (int q = 0; q < PPW; ++q) {
    const int pi = wid + 8 * q;       // [0,16) exactly
    const int isA = pi < APL;
    const int rtl = (isA ? pi : pi - APL) >> 2;
    const int pb  = pi & 3;
    const unsigned short* base =
        isA ? (Am + (uint64_t)(art0 + rtl) * Kt * 4096)
            : (Bm + (uint64_t)(brt0 + rtl) * Kt * 4096);
    srcb[q] = base + pb * 512 + lane * 8;
    ldso[q] = pi * 512;
  }

  int aoff[IF], boff[4];
#pragma unroll
  for (int i = 0; i < IF; ++i) {
    const int row = wV * 32 + i * 16 + fr;
    aoff[i] = ((row >> 6) * 4 + q4) * 512 + (row & 63) * 8;
  }
#pragma unroll
  for (int j = 0; j < 4; ++j)
    boff[j] = (APL + wM * 4 + q4) * 512 + (j * 16 + fr) * 8;

  f32x4 acc[IF][4] = {};

#pragma unroll
  for (int pt = 0; pt < 3; ++pt)
#pragma unroll
    for (int q = 0; q < PPW; ++q)
      load_lds16(srcb[q] + pt * 2048, smem + pt * BUFS + ldso[q]);
  vmw<4>();  // tile 0 landed (2 loads/wave/tile, 2 tiles in flight)
  SBAR();

  // ---- main loop: ONE barrier per K-tile ----
#pragma unroll 4
  for (int tt = 0; tt < NT; ++tt) {
    const unsigned short* buf = smem + (tt & 3) * BUFS;
    s16x8 bfr[4], afr[IF];
#pragma unroll
    for (int j = 0; j < 4; ++j) bfr[j] = *(const s16x8*)(buf + boff[j]);
#pragma unroll
    for (int i = 0; i < IF; ++i) afr[i] = *(const s16x8*)(buf + aoff[i]);
    if (tt + 3 < NT) {
      unsigned short* pdst = smem + ((tt + 3) & 3) * BUFS;
#pragma unroll
      for (int q = 0; q < PPW; ++q)
        load_lds16(srcb[q] + (uint64_t)(tt + 3) * 2048, pdst + ldso[q]);
    }
    __builtin_amdgcn_s_setprio(1);
#pragma unroll
    for (int i = 0; i < IF; ++i)
#pragma unroll
      for (int j = 0; j < 4; ++j)
        acc[i][j] = __builtin_amdgcn_mfma_f32_16x16x32_bf16(afr[i], bfr[j],
                                                            acc[i][j], 0, 0, 0);
    __builtin_amdgcn_s_setprio(0);
    if (tt + 3 < NT) {
      vmw<4>();        // leave tiles tt+2, tt+3 in flight
    } else if (tt + 2 < NT) {
      vmw<2>();        // leave tile tt+2 in flight
    } else {
      vmw<0>();
    }
    SBAR();
  }

  // ---- epilogue: G-tile [128][128] -> LDS stride 136, conv+GLU+max ----
  __syncthreads();
  {
    const int rr = q4 * 4;
#pragma unroll
    for (int i = 0; i < IF; ++i)
#pragma unroll
      for (int j = 0; j < 4; ++j) {
        const int col = wM * 64 + j * 16 + fr;
#pragma unroll
        for (int r = 0; r < 4; ++r) {
          const int row = wV * 32 + i * 16 + rr + r;
          smem[row * 136 + col] = f2bf(acc[i][j][r]);
        }
      }
  }
  __syncthreads();

  s16x8 wf[2][8];
#pragma unroll
  for (int ksi = 0; ksi < 2; ++ksi)
#pragma unroll
    for (int j = 0; j < 8; ++j)
      wf[ksi][j] = *(const s16x8*)(W + (j * 16 + fr) * 64 + ksi * 32 + q4 * 8);
  float bj[8];
#pragma unroll
  for (int j = 0; j < 8; ++j) bj[j] = bf2f(bias[j * 16 + fr]);

  {
    const int rb = wid;              // 8 row-blocks of 16 v-rows
#pragma unroll
    for (int bb = 0; bb < 2; ++bb) {
      f32x4 acc2[8] = {};
#pragma unroll
      for (int ksi = 0; ksi < 2; ++ksi) {
        s16x8 af = *(const s16x8*)(smem + (rb * 16 + fr) * 136 + bb * 64 +
                                   ksi * 32 + q4 * 8);
#pragma unroll
        for (int j = 0; j < 8; ++j)
          acc2[j] = __builtin_amdgcn_mfma_f32_16x16x32_bf16(af, wf[ksi][j],
                                                            acc2[j], 0, 0, 0);
      }
      const int v = v0 + rb * 16 + q4 * 4;
#pragma unroll
      for (int j = 0; j < 4; ++j) {
        const int o = j * 16 + fr;
        const int hrow = m0 + bb * 64 + o;
        const int c = 1024 + v;  // H1 col; Kt of H1 is 48
        u16x4 hv = *(const u16x4*)(Hprev +
            ((uint64_t)(hrow >> 6) * 48 + (c >> 6)) * 4096 +
            ((c >> 3) & 7) * 512 + (hrow & 63) * 8 + (c & 7));
        float* op = outp + (uint64_t)v * 4096 + hrow;
#pragma unroll
        for (int r = 0; r < 4; ++r) {
          float lhs = acc2[j][r] + bj[j];
          float rhs = acc2[j + 4][r] + bj[j + 4];
          float sg = 1.0f / (1.0f + __expf(-rhs));
          op[(uint64_t)r * 4096] = fmaxf(lhs * sg, bf2f(hv[r]));
        }
      }
    }
  }
}

// ---------------------------------------------------------------------------
extern "C" void kernel_launch(void* const* d_in, const int* in_sizes, int n_in,
                              void* d_out, int out_size, void* d_ws, size_t ws_size,
                              hipStream_t stream) {
  (void)in_sizes; (void)n_in; (void)out_size; (void)ws_size;
  const void* x  = d_in[0];  // [3072][64][64]
  const void* A  = d_in[1];  // [3072][3072]
  const void* W0 = d_in[2];  // [128][64]
  const void* b0 = d_in[3];  // [128]
  const void* W1 = d_in[4];  // [128][64]
  const void* b1 = d_in[5];  // [128]
  float* out = (float*)d_out;  // [1024][64][64] fp32

  char* ws = (char*)d_ws;
  unsigned short* Xtp = (unsigned short*)(ws + 0);         // 25165824 B
  unsigned short* Abp = (unsigned short*)(ws + 25165824);  // 18874368 B
  unsigned short* Wb  = (unsigned short*)(ws + 44040192);  // 33280 B
  unsigned short* H1p = (unsigned short*)(ws + 44105728);  // 25165824 B -> end 69271552

  // P0: transpose (3072 blocks) + packA (2304) + cvtW (1)
  k_prep<<<5377, 256, 0, stream>>>(x, A, W0, b0, W1, b1, Xtp, Abp, Wb);
  // K1: H1 = GLU(W0.(A.Xt^T)+b0), 192x256 tiles -> 256 blocks = 1/CU.
  k1_gemm_glu<<<dim3(16, 16), 512, 0, stream>>>(Abp, Xtp, Wb, Wb + 8192, H1p);
  // K3: out = max(H1 mid, GLU(W1.(A2.H1^T)+b1)), 128x128 tiles -> 8x32 =
  // 256 blocks = full chip at min staging volume. Plain Abp (offset inside).
  k3_gemm_glu<<<dim3(8, 32), 512, 0, stream>>>(
      Abp, H1p, Wb + 8320, Wb + 16512, H1p, out);
}